// Round 5
// baseline (638.317 us; speedup 1.0000x reference)
//
#include <hip/hip_runtime.h>
#include <hip/hip_fp16.h>

// ResidualDenoiser: 4 chained GEMMs + BN/ReLU + ragged segment softmax.
// Activations live in one persistent fp16 buffer H[8192][3328] laid out
// [A3 | A2 | A1 | A0=x] so each layer's concatenated input is H + colOff.
//   layer0: in H+3072 (K= 256) -> out cols 2048:3072
//   layer1: in H+2048 (K=1280) -> out cols 1024:2048
//   layer2: in H+1024 (K=2304) -> out cols    0:1024
//   layer3: in H+0    (K=3328) -> splitK=4 atomicAdd fp32 into out (bias
//           pre-applied by prep); LAST contributor block per 128-row tile
//           runs the ragged segment softmax in-place (fused, no extra pass).
// GEMM tile: BM=BN=128, BK=64, 4 waves (2x2) each 64x64, 16x16x32 f16 MFMA
// (R2's measured-best config; R3's BM=64 and R4's megakernel both regressed).

#define LDH 3328
#define NROWS 8192

typedef _Float16 f16x8 __attribute__((ext_vector_type(8)));
typedef _Float16 f16x4 __attribute__((ext_vector_type(4)));
typedef float f32x4 __attribute__((ext_vector_type(4)));

__constant__ int c_bnd[11] = {0, 2, 5, 10, 18, 31, 52, 86, 141, 230, 256};

// async global->LDS, 16B per lane; LDS dest is wave-uniform base + lane*16.
__device__ __forceinline__ void async_cp16(const _Float16* g, _Float16* l) {
  __builtin_amdgcn_global_load_lds(
      (__attribute__((address_space(1))) void*)g,
      (__attribute__((address_space(3))) void*)l, 16, 0, 0);
}

__device__ __forceinline__ _Float16 f2h(float f) { return (_Float16)f; }

// ---------------------------------------------------------------------------
// prep: weights fp32->fp16 (contiguous), x staged into H, out = bias,
// per-row-tile arrival counters zeroed. One element-group per thread.
__global__ void prep_kernel(const float* __restrict__ s0,
                            const float* __restrict__ s1,
                            const float* __restrict__ s2,
                            const float* __restrict__ s3,
                            const float* __restrict__ x,
                            const float* __restrict__ b3,
                            _Float16* __restrict__ d0,
                            _Float16* __restrict__ d1,
                            _Float16* __restrict__ d2,
                            _Float16* __restrict__ d3,
                            _Float16* __restrict__ H, float* __restrict__ out,
                            unsigned* __restrict__ cnt, int n0, int n1,
                            int n2, int n3, int n4, int n5) {
  int i = blockIdx.x * blockDim.x + threadIdx.x;
  if (blockIdx.x == 0 && threadIdx.x < 64) cnt[threadIdx.x] = 0u;
  if (i >= n5) return;
  if (i >= n4) {  // out[8192][256] = broadcast bias b3
    const int j = i - n4;
    const int c = (j & 63) * 4;
    *(float4*)&out[(size_t)j * 4] = *(const float4*)&b3[c];
    return;
  }
  if (i >= n3) {  // x[8192,256] -> H[:, 3072:3328]
    const int j = i - n3;
    const int row = j >> 6;
    const int c = (j & 63) * 4;
    const float4 v = *(const float4*)&x[(size_t)j * 4];
    f16x4 h = {f2h(v.x), f2h(v.y), f2h(v.z), f2h(v.w)};
    *(f16x4*)&H[(size_t)row * LDH + 3072 + c] = h;
    return;
  }
  const float* s;
  _Float16* d;
  if (i < n0) {
    s = s0; d = d0;
  } else if (i < n1) {
    s = s1 - (size_t)n0 * 4; d = d1 - (size_t)n0 * 4;
  } else if (i < n2) {
    s = s2 - (size_t)n1 * 4; d = d2 - (size_t)n1 * 4;
  } else {
    s = s3 - (size_t)n2 * 4; d = d3 - (size_t)n2 * 4;
  }
  const float4 v = *(const float4*)&s[(size_t)i * 4];
  f16x4 h = {f2h(v.x), f2h(v.y), f2h(v.z), f2h(v.w)};
  *(f16x4*)&d[(size_t)i * 4] = h;
}

// ---------------------------------------------------------------------------
// Fused layers 0-2: C = relu(bn(A[128,K] @ W[128,K]^T)) -> fp16 into H.
// Grid dim3(64,8): 64 row-tiles x 8 col-tiles of 128.
__launch_bounds__(256, 4) __global__
void gemm_bn_kernel(const _Float16* __restrict__ A, int K,
                    const _Float16* __restrict__ W,
                    const float* __restrict__ bias,
                    const float* __restrict__ g, const float* __restrict__ be,
                    const float* __restrict__ rm,
                    const float* __restrict__ rv, _Float16* __restrict__ outH,
                    int outOff) {
  __shared__ _Float16 Alds[128 * 64];
  __shared__ _Float16 Blds[128 * 64];

  const int tid = threadIdx.x;
  const int lane = tid & 63;
  const int wave = tid >> 6;          // 0..3
  const int wr = wave >> 1;           // 64-row half
  const int wc = wave & 1;            // 64-col half
  const int row0 = blockIdx.x * 128;  // M block
  const int col0 = blockIdx.y * 128;  // N block
  const int lr = lane >> 3;  // staging: 8 rows x 8 16B-chunks
  const int ls = lane & 7;
  const int lc = ls ^ lr;    // XOR swizzle (conflict-free ds_read_b128)
  const int fr = lane & 15;  // fragment row/col
  const int q = lane >> 4;   // quad

  f32x4 acc[4][4] = {};

  for (int k0 = 0; k0 < K; k0 += 64) {
    __syncthreads();
#pragma unroll
    for (int it = 0; it < 4; ++it) {
      const int rl = it * 32 + wave * 8;
      async_cp16(A + (size_t)(row0 + rl + lr) * LDH + k0 + lc * 8,
                 &Alds[rl * 64]);
      async_cp16(W + (size_t)(col0 + rl + lr) * K + k0 + lc * 8,
                 &Blds[rl * 64]);
    }
    __syncthreads();

#pragma unroll
    for (int kq = 0; kq < 2; ++kq) {
      f16x8 av[4], bv[4];
#pragma unroll
      for (int t = 0; t < 4; ++t) {
        const int ra = wr * 64 + t * 16 + fr;
        av[t] = *(const f16x8*)&Alds[ra * 64 + (((q + 4 * kq) ^ (ra & 7)) * 8)];
        const int rb = wc * 64 + t * 16 + fr;
        bv[t] = *(const f16x8*)&Blds[rb * 64 + (((q + 4 * kq) ^ (rb & 7)) * 8)];
      }
#pragma unroll
      for (int tm = 0; tm < 4; ++tm)
#pragma unroll
        for (int tn = 0; tn < 4; ++tn)
          acc[tm][tn] = __builtin_amdgcn_mfma_f32_16x16x32_f16(
              av[tm], bv[tn], acc[tm][tn], 0, 0, 0);
    }
  }

  // Epilogue. C/D layout: col = lane&15, row = (lane>>4)*4 + reg.
#pragma unroll
  for (int tn = 0; tn < 4; ++tn) {
    const int n = col0 + wc * 64 + tn * 16 + fr;
    const float alpha = g[n] * rsqrtf(rv[n] + 1e-5f);
    const float beta = (bias[n] - rm[n]) * alpha + be[n];
#pragma unroll
    for (int tm = 0; tm < 4; ++tm) {
      const int rbase = row0 + wr * 64 + tm * 16 + q * 4;
#pragma unroll
      for (int r = 0; r < 4; ++r) {
        float v = acc[tm][tn][r] * alpha + beta;
        v = fmaxf(v, 0.0f);
        outH[(size_t)(rbase + r) * LDH + outOff + n] = f2h(v);
      }
    }
  }
}

// ---------------------------------------------------------------------------
// Layer 3 + fused softmax. Grid dim3(64,8): by -> cb=by&1 (col tile of 128),
// ks=by>>1 (splitK slice of 832). Partials atomicAdd into out (bias
// pre-applied). The 8th contributor for a row-tile runs segment softmax on
// its 128 rows.
__launch_bounds__(256, 4) __global__
void gemm_out_kernel(const _Float16* __restrict__ A,
                     const _Float16* __restrict__ W, float* __restrict__ out,
                     const int* __restrict__ seg, unsigned* __restrict__ cnt) {
  __shared__ __align__(16) unsigned char smem[32768];
  _Float16* Alds = (_Float16*)smem;
  _Float16* Blds = (_Float16*)(smem + 16384);

  const int tid = threadIdx.x;
  const int lane = tid & 63;
  const int wave = tid >> 6;
  const int wr = wave >> 1;
  const int wc = wave & 1;
  const int bx = blockIdx.x;          // row tile
  const int row0 = bx * 128;
  const int cb = blockIdx.y & 1;      // col tile (N=256)
  const int ks = blockIdx.y >> 1;     // splitK slice
  const int col0 = cb * 128;
  const int k0b = ks * 832;
  const int k0e = k0b + 832;
  const int lr = lane >> 3;
  const int ls = lane & 7;
  const int lc = ls ^ lr;
  const int fr = lane & 15;
  const int q = lane >> 4;
  const int K = 3328;

  f32x4 acc[4][4] = {};

  for (int k0 = k0b; k0 < k0e; k0 += 64) {
    __syncthreads();
#pragma unroll
    for (int it = 0; it < 4; ++it) {
      const int rl = it * 32 + wave * 8;
      async_cp16(A + (size_t)(row0 + rl + lr) * LDH + k0 + lc * 8,
                 &Alds[rl * 64]);
      async_cp16(W + (size_t)(col0 + rl + lr) * K + k0 + lc * 8,
                 &Blds[rl * 64]);
    }
    __syncthreads();

#pragma unroll
    for (int kq = 0; kq < 2; ++kq) {
      f16x8 av[4], bv[4];
#pragma unroll
      for (int t = 0; t < 4; ++t) {
        const int ra = wr * 64 + t * 16 + fr;
        av[t] = *(const f16x8*)&Alds[ra * 64 + (((q + 4 * kq) ^ (ra & 7)) * 8)];
        const int rb = wc * 64 + t * 16 + fr;
        bv[t] = *(const f16x8*)&Blds[rb * 64 + (((q + 4 * kq) ^ (rb & 7)) * 8)];
      }
#pragma unroll
      for (int tm = 0; tm < 4; ++tm)
#pragma unroll
        for (int tn = 0; tn < 4; ++tn)
          acc[tm][tn] = __builtin_amdgcn_mfma_f32_16x16x32_f16(
              av[tm], bv[tn], acc[tm][tn], 0, 0, 0);
    }
  }

#pragma unroll
  for (int tn = 0; tn < 4; ++tn) {
    const int n = col0 + wc * 64 + tn * 16 + fr;
#pragma unroll
    for (int tm = 0; tm < 4; ++tm) {
      const int rbase = row0 + wr * 64 + tm * 16 + q * 4;
#pragma unroll
      for (int r = 0; r < 4; ++r)
        atomicAdd(&out[(size_t)(rbase + r) * 256 + n], acc[tm][tn][r]);
    }
  }

  // ---- last-arriver fused softmax for rows [row0, row0+128) ----
  __threadfence();   // release: order my partial adds before the count
  __syncthreads();   // all waves' atomics issued & drained (vmcnt(0))
  __shared__ unsigned last;
  if (tid == 0) last = (atomicAdd(&cnt[bx], 1u) == 7u) ? 1u : 0u;
  __syncthreads();
  if (!last) return;
  __threadfence();   // acquire: invalidate caches; see peers' partials

  float(*vals)[256] = (float(*)[256])smem;
  float(*red)[16] = (float(*)[16])(smem + 8192);
  const int w = wave;
  const int l = lane;
  const int4 s4 = *(const int4*)&seg[l * 4];
#pragma unroll 1
  for (int batch = 0; batch < 32; ++batch) {
    const int row = row0 + batch * 4 + w;
    __syncthreads();
    float4 v = *(float4*)&out[(size_t)row * 256 + l * 4];
    *(float4*)&vals[w][l * 4] = v;
    __syncthreads();
    if (l < 10) {
      float m = -1e30f;
      for (int j = c_bnd[l]; j < c_bnd[l + 1]; ++j) m = fmaxf(m, vals[w][j]);
      red[w][l] = m;
    }
    __syncthreads();
    float4 e;
    e.x = expf(v.x - red[w][s4.x]);
    e.y = expf(v.y - red[w][s4.y]);
    e.z = expf(v.z - red[w][s4.z]);
    e.w = expf(v.w - red[w][s4.w]);
    *(float4*)&vals[w][l * 4] = e;
    __syncthreads();
    if (l < 10) {
      float s = 0.0f;
      for (int j = c_bnd[l]; j < c_bnd[l + 1]; ++j) s += vals[w][j];
      red[w][l] = s;
    }
    __syncthreads();
    float4 o;
    o.x = e.x / red[w][s4.x];
    o.y = e.y / red[w][s4.y];
    o.z = e.z / red[w][s4.z];
    o.w = e.w / red[w][s4.w];
    *(float4*)&out[(size_t)row * 256 + l * 4] = o;
  }
}

// ---------------------------------------------------------------------------
extern "C" void kernel_launch(void* const* d_in, const int* in_sizes, int n_in,
                              void* d_out, int out_size, void* d_ws,
                              size_t ws_size, hipStream_t stream) {
  const float* x = (const float*)d_in[0];
  const float* W0 = (const float*)d_in[1];
  const float* b0 = (const float*)d_in[2];
  const float* g0 = (const float*)d_in[3];
  const float* be0 = (const float*)d_in[4];
  const float* rm0 = (const float*)d_in[5];
  const float* rv0 = (const float*)d_in[6];
  const float* W1 = (const float*)d_in[7];
  const float* b1 = (const float*)d_in[8];
  const float* g1 = (const float*)d_in[9];
  const float* be1 = (const float*)d_in[10];
  const float* rm1 = (const float*)d_in[11];
  const float* rv1 = (const float*)d_in[12];
  const float* W2 = (const float*)d_in[13];
  const float* b2 = (const float*)d_in[14];
  const float* g2 = (const float*)d_in[15];
  const float* be2 = (const float*)d_in[16];
  const float* rm2 = (const float*)d_in[17];
  const float* rv2 = (const float*)d_in[18];
  const float* W3 = (const float*)d_in[19];
  const float* b3 = (const float*)d_in[20];
  const int* seg = (const int*)d_in[21];
  float* out = (float*)d_out;

  // ws (fp16): H[8192*3328] | Wh0 | Wh1 | Wh2 | Wh3 | counters (~64.1 MB)
  _Float16* H = (_Float16*)d_ws;
  size_t off = (size_t)NROWS * LDH;
  _Float16* Wh0 = H + off; off += 1024 * 256;
  _Float16* Wh1 = H + off; off += 1024 * 1280;
  _Float16* Wh2 = H + off; off += 1024 * 2304;
  _Float16* Wh3 = H + off; off += 256 * 3328;
  unsigned* cnt = (unsigned*)(H + off);

  // cumulative float4 counts: W0, W1, W2, W3, x, out-init
  const int n0 = 65536, n1 = n0 + 327680, n2 = n1 + 589824, n3 = n2 + 212992;
  const int n4 = n3 + 524288, n5 = n4 + 524288;
  prep_kernel<<<(n5 + 255) / 256, 256, 0, stream>>>(
      W0, W1, W2, W3, x, b3, Wh0, Wh1, Wh2, Wh3, H, out, cnt, n0, n1, n2, n3,
      n4, n5);

  dim3 blk(256);
  gemm_bn_kernel<<<dim3(64, 8), blk, 0, stream>>>(
      H + 3072, 256, Wh0, b0, g0, be0, rm0, rv0, H, 2048);
  gemm_bn_kernel<<<dim3(64, 8), blk, 0, stream>>>(
      H + 2048, 1280, Wh1, b1, g1, be1, rm1, rv1, H, 1024);
  gemm_bn_kernel<<<dim3(64, 8), blk, 0, stream>>>(
      H + 1024, 2304, Wh2, b2, g2, be2, rm2, rv2, H, 0);
  gemm_out_kernel<<<dim3(64, 8), blk, 0, stream>>>(H, Wh3, out, seg, cnt);
}

// Round 6
// 626.595 us; speedup vs baseline: 1.0187x; 1.0187x over previous
//
#include <hip/hip_runtime.h>
#include <hip/hip_fp16.h>

// ResidualDenoiser: 4 chained GEMMs + BN/ReLU + ragged segment softmax.
// Activations live in one persistent fp16 buffer H[8192][3328] laid out
// [A3 | A2 | A1 | A0=x] so each layer's concatenated input is H + colOff.
//   layer0: in H+3072 (K= 256) -> out cols 2048:3072
//   layer1: in H+2048 (K=1280) -> out cols 1024:2048
//   layer2: in H+1024 (K=2304) -> out cols    0:1024
//   layer3: in H+0    (K=3328) -> splitK=4 atomicAdd fp32 into out (bias
//           pre-applied by prep); LAST contributor block per 128-row tile
//           runs the ragged segment softmax in-place.
// Sync lessons (R4/R5 measured): NO per-thread __threadfence in the data
// path (wbl2 storms spill atomics to HBM, 455 us). Contributors rely on the
// compiler's vmcnt(0)-before-s_barrier drain + one ACQ_REL counter RMW by
// tid0; only the last block executes an ACQUIRE-only fence (buffer_inv, no
// writeback) before reading peers' partials.
// GEMM tile: BM=BN=128, BK=64, 4 waves (2x2) each 64x64, 16x16x32 f16 MFMA
// (R2's measured-best config; R3 BM=64 and R4 megakernel both regressed).

#define LDH 3328
#define NROWS 8192

typedef _Float16 f16x8 __attribute__((ext_vector_type(8)));
typedef _Float16 f16x4 __attribute__((ext_vector_type(4)));
typedef float f32x4 __attribute__((ext_vector_type(4)));

__constant__ int c_bnd[11] = {0, 2, 5, 10, 18, 31, 52, 86, 141, 230, 256};

// async global->LDS, 16B per lane; LDS dest is wave-uniform base + lane*16.
__device__ __forceinline__ void async_cp16(const _Float16* g, _Float16* l) {
  __builtin_amdgcn_global_load_lds(
      (__attribute__((address_space(1))) void*)g,
      (__attribute__((address_space(3))) void*)l, 16, 0, 0);
}

__device__ __forceinline__ _Float16 f2h(float f) { return (_Float16)f; }

// ---------------------------------------------------------------------------
// prep: weights fp32->fp16 (contiguous), x staged into H, out = bias,
// per-row-tile arrival counters zeroed. One float4-group per thread.
__global__ void prep_kernel(const float* __restrict__ s0,
                            const float* __restrict__ s1,
                            const float* __restrict__ s2,
                            const float* __restrict__ s3,
                            const float* __restrict__ x,
                            const float* __restrict__ b3,
                            _Float16* __restrict__ d0,
                            _Float16* __restrict__ d1,
                            _Float16* __restrict__ d2,
                            _Float16* __restrict__ d3,
                            _Float16* __restrict__ H, float* __restrict__ out,
                            unsigned* __restrict__ cnt, int n0, int n1,
                            int n2, int n3, int n4, int n5) {
  int i = blockIdx.x * blockDim.x + threadIdx.x;
  if (blockIdx.x == 0 && threadIdx.x < 64) cnt[threadIdx.x] = 0u;
  if (i >= n5) return;
  if (i >= n4) {  // out[8192][256] = broadcast bias b3
    const int j = i - n4;
    const int c = (j & 63) * 4;
    *(float4*)&out[(size_t)j * 4] = *(const float4*)&b3[c];
    return;
  }
  if (i >= n3) {  // x[8192,256] -> H[:, 3072:3328]
    const int j = i - n3;
    const int row = j >> 6;
    const int c = (j & 63) * 4;
    const float4 v = *(const float4*)&x[(size_t)j * 4];
    f16x4 h = {f2h(v.x), f2h(v.y), f2h(v.z), f2h(v.w)};
    *(f16x4*)&H[(size_t)row * LDH + 3072 + c] = h;
    return;
  }
  const float* s;
  _Float16* d;
  if (i < n0) {
    s = s0; d = d0;
  } else if (i < n1) {
    s = s1 - (size_t)n0 * 4; d = d1 - (size_t)n0 * 4;
  } else if (i < n2) {
    s = s2 - (size_t)n1 * 4; d = d2 - (size_t)n1 * 4;
  } else {
    s = s3 - (size_t)n2 * 4; d = d3 - (size_t)n2 * 4;
  }
  const float4 v = *(const float4*)&s[(size_t)i * 4];
  f16x4 h = {f2h(v.x), f2h(v.y), f2h(v.z), f2h(v.w)};
  *(f16x4*)&d[(size_t)i * 4] = h;
}

// ---------------------------------------------------------------------------
// Layers 0-2: C = relu(bn(A[128,K] @ W[128,K]^T)) -> fp16 into H.
// Grid dim3(64,8): 64 row-tiles x 8 col-tiles of 128. (R2's exact body.)
__launch_bounds__(256, 4) __global__
void gemm_bn_kernel(const _Float16* __restrict__ A, int K,
                    const _Float16* __restrict__ W,
                    const float* __restrict__ bias,
                    const float* __restrict__ g, const float* __restrict__ be,
                    const float* __restrict__ rm,
                    const float* __restrict__ rv, _Float16* __restrict__ outH,
                    int outOff) {
  __shared__ _Float16 Alds[128 * 64];
  __shared__ _Float16 Blds[128 * 64];

  const int tid = threadIdx.x;
  const int lane = tid & 63;
  const int wave = tid >> 6;          // 0..3
  const int wr = wave >> 1;           // 64-row half
  const int wc = wave & 1;            // 64-col half
  const int row0 = blockIdx.x * 128;  // M block
  const int col0 = blockIdx.y * 128;  // N block
  const int lr = lane >> 3;  // staging: 8 rows x 8 16B-chunks
  const int ls = lane & 7;
  const int lc = ls ^ lr;    // XOR swizzle (conflict-free ds_read_b128)
  const int fr = lane & 15;  // fragment row/col
  const int q = lane >> 4;   // quad

  f32x4 acc[4][4] = {};

  for (int k0 = 0; k0 < K; k0 += 64) {
    __syncthreads();
#pragma unroll
    for (int it = 0; it < 4; ++it) {
      const int rl = it * 32 + wave * 8;
      async_cp16(A + (size_t)(row0 + rl + lr) * LDH + k0 + lc * 8,
                 &Alds[rl * 64]);
      async_cp16(W + (size_t)(col0 + rl + lr) * K + k0 + lc * 8,
                 &Blds[rl * 64]);
    }
    __syncthreads();

#pragma unroll
    for (int kq = 0; kq < 2; ++kq) {
      f16x8 av[4], bv[4];
#pragma unroll
      for (int t = 0; t < 4; ++t) {
        const int ra = wr * 64 + t * 16 + fr;
        av[t] = *(const f16x8*)&Alds[ra * 64 + (((q + 4 * kq) ^ (ra & 7)) * 8)];
        const int rb = wc * 64 + t * 16 + fr;
        bv[t] = *(const f16x8*)&Blds[rb * 64 + (((q + 4 * kq) ^ (rb & 7)) * 8)];
      }
#pragma unroll
      for (int tm = 0; tm < 4; ++tm)
#pragma unroll
        for (int tn = 0; tn < 4; ++tn)
          acc[tm][tn] = __builtin_amdgcn_mfma_f32_16x16x32_f16(
              av[tm], bv[tn], acc[tm][tn], 0, 0, 0);
    }
  }

  // Epilogue. C/D layout: col = lane&15, row = (lane>>4)*4 + reg.
#pragma unroll
  for (int tn = 0; tn < 4; ++tn) {
    const int n = col0 + wc * 64 + tn * 16 + fr;
    const float alpha = g[n] * rsqrtf(rv[n] + 1e-5f);
    const float beta = (bias[n] - rm[n]) * alpha + be[n];
#pragma unroll
    for (int tm = 0; tm < 4; ++tm) {
      const int rbase = row0 + wr * 64 + tm * 16 + q * 4;
#pragma unroll
      for (int r = 0; r < 4; ++r) {
        float v = acc[tm][tn][r] * alpha + beta;
        v = fmaxf(v, 0.0f);
        outH[(size_t)(rbase + r) * LDH + outOff + n] = f2h(v);
      }
    }
  }
}

// ---------------------------------------------------------------------------
// Layer 3 + fused softmax. Grid dim3(64,8): cb=by&1 (col tile), ks=by>>1
// (splitK slice of 832). Partials atomicAdd into out (bias pre-applied).
// The 8th contributor per row-tile runs segment softmax on its 128 rows.
__launch_bounds__(256, 4) __global__
void gemm_out_kernel(const _Float16* __restrict__ A,
                     const _Float16* __restrict__ W, float* __restrict__ out,
                     const int* __restrict__ seg, unsigned* __restrict__ cnt) {
  __shared__ __align__(16) unsigned char smem[32768];
  _Float16* Alds = (_Float16*)smem;
  _Float16* Blds = (_Float16*)(smem + 16384);

  const int tid = threadIdx.x;
  const int lane = tid & 63;
  const int wave = tid >> 6;
  const int wr = wave >> 1;
  const int wc = wave & 1;
  const int bx = blockIdx.x;       // row tile
  const int row0 = bx * 128;
  const int cb = blockIdx.y & 1;   // col tile (N=256)
  const int ks = blockIdx.y >> 1;  // splitK slice
  const int col0 = cb * 128;
  const int k0b = ks * 832;
  const int k0e = k0b + 832;
  const int lr = lane >> 3;
  const int ls = lane & 7;
  const int lc = ls ^ lr;
  const int fr = lane & 15;
  const int q = lane >> 4;
  const int K = 3328;

  f32x4 acc[4][4] = {};

  for (int k0 = k0b; k0 < k0e; k0 += 64) {
    __syncthreads();
#pragma unroll
    for (int it = 0; it < 4; ++it) {
      const int rl = it * 32 + wave * 8;
      async_cp16(A + (size_t)(row0 + rl + lr) * LDH + k0 + lc * 8,
                 &Alds[rl * 64]);
      async_cp16(W + (size_t)(col0 + rl + lr) * K + k0 + lc * 8,
                 &Blds[rl * 64]);
    }
    __syncthreads();

#pragma unroll
    for (int kq = 0; kq < 2; ++kq) {
      f16x8 av[4], bv[4];
#pragma unroll
      for (int t = 0; t < 4; ++t) {
        const int ra = wr * 64 + t * 16 + fr;
        av[t] = *(const f16x8*)&Alds[ra * 64 + (((q + 4 * kq) ^ (ra & 7)) * 8)];
        const int rb = wc * 64 + t * 16 + fr;
        bv[t] = *(const f16x8*)&Blds[rb * 64 + (((q + 4 * kq) ^ (rb & 7)) * 8)];
      }
#pragma unroll
      for (int tm = 0; tm < 4; ++tm)
#pragma unroll
        for (int tn = 0; tn < 4; ++tn)
          acc[tm][tn] = __builtin_amdgcn_mfma_f32_16x16x32_f16(
              av[tm], bv[tn], acc[tm][tn], 0, 0, 0);
    }
  }

#pragma unroll
  for (int tn = 0; tn < 4; ++tn) {
    const int n = col0 + wc * 64 + tn * 16 + fr;
#pragma unroll
    for (int tm = 0; tm < 4; ++tm) {
      const int rbase = row0 + wr * 64 + tm * 16 + q * 4;
#pragma unroll
      for (int r = 0; r < 4; ++r)
        atomicAdd(&out[(size_t)(rbase + r) * 256 + n], acc[tm][tn][r]);
    }
  }

  // ---- last-arriver fused softmax for rows [row0, row0+128) ----
  // NO fences here: device-scope atomics complete at the coherent point and
  // the compiler's s_waitcnt vmcnt(0) before s_barrier drains them.
  __syncthreads();
  volatile unsigned* flag = (volatile unsigned*)(smem + 16384);  // Blds dead
  if (tid == 0)
    *flag = (__hip_atomic_fetch_add(&cnt[bx], 1u, __ATOMIC_ACQ_REL,
                                    __HIP_MEMORY_SCOPE_AGENT) == 7u)
                ? 1u
                : 0u;
  __syncthreads();
  if (*flag == 0u) return;
  // acquire-only (buffer_inv, no wbl2): see peers' partials, cheap.
  __builtin_amdgcn_fence(__ATOMIC_ACQUIRE, "agent");

  float(*vals)[256] = (float(*)[256])smem;
  float(*red)[16] = (float(*)[16])(smem + 8192);
  const int w = wave;
  const int l = lane;
  const int4 s4 = *(const int4*)&seg[l * 4];
#pragma unroll 1
  for (int batch = 0; batch < 32; ++batch) {
    const int row = row0 + batch * 4 + w;
    __syncthreads();
    float4 v = *(float4*)&out[(size_t)row * 256 + l * 4];
    *(float4*)&vals[w][l * 4] = v;
    __syncthreads();
    if (l < 10) {
      float m = -1e30f;
      for (int j = c_bnd[l]; j < c_bnd[l + 1]; ++j) m = fmaxf(m, vals[w][j]);
      red[w][l] = m;
    }
    __syncthreads();
    float4 e;
    e.x = expf(v.x - red[w][s4.x]);
    e.y = expf(v.y - red[w][s4.y]);
    e.z = expf(v.z - red[w][s4.z]);
    e.w = expf(v.w - red[w][s4.w]);
    *(float4*)&vals[w][l * 4] = e;
    __syncthreads();
    if (l < 10) {
      float s = 0.0f;
      for (int j = c_bnd[l]; j < c_bnd[l + 1]; ++j) s += vals[w][j];
      red[w][l] = s;
    }
    __syncthreads();
    float4 o;
    o.x = e.x / red[w][s4.x];
    o.y = e.y / red[w][s4.y];
    o.z = e.z / red[w][s4.z];
    o.w = e.w / red[w][s4.w];
    *(float4*)&out[(size_t)row * 256 + l * 4] = o;
  }
}

// ---------------------------------------------------------------------------
extern "C" void kernel_launch(void* const* d_in, const int* in_sizes, int n_in,
                              void* d_out, int out_size, void* d_ws,
                              size_t ws_size, hipStream_t stream) {
  const float* x = (const float*)d_in[0];
  const float* W0 = (const float*)d_in[1];
  const float* b0 = (const float*)d_in[2];
  const float* g0 = (const float*)d_in[3];
  const float* be0 = (const float*)d_in[4];
  const float* rm0 = (const float*)d_in[5];
  const float* rv0 = (const float*)d_in[6];
  const float* W1 = (const float*)d_in[7];
  const float* b1 = (const float*)d_in[8];
  const float* g1 = (const float*)d_in[9];
  const float* be1 = (const float*)d_in[10];
  const float* rm1 = (const float*)d_in[11];
  const float* rv1 = (const float*)d_in[12];
  const float* W2 = (const float*)d_in[13];
  const float* b2 = (const float*)d_in[14];
  const float* g2 = (const float*)d_in[15];
  const float* be2 = (const float*)d_in[16];
  const float* rm2 = (const float*)d_in[17];
  const float* rv2 = (const float*)d_in[18];
  const float* W3 = (const float*)d_in[19];
  const float* b3 = (const float*)d_in[20];
  const int* seg = (const int*)d_in[21];
  float* out = (float*)d_out;

  // ws (fp16): H[8192*3328] | Wh0 | Wh1 | Wh2 | Wh3 | counters (~64.1 MB)
  _Float16* H = (_Float16*)d_ws;
  size_t off = (size_t)NROWS * LDH;
  _Float16* Wh0 = H + off; off += 1024 * 256;
  _Float16* Wh1 = H + off; off += 1024 * 1280;
  _Float16* Wh2 = H + off; off += 1024 * 2304;
  _Float16* Wh3 = H + off; off += 256 * 3328;
  unsigned* cnt = (unsigned*)(H + off);

  // cumulative float4 counts: W0, W1, W2, W3, x, out-init
  const int n0 = 65536, n1 = n0 + 327680, n2 = n1 + 589824, n3 = n2 + 212992;
  const int n4 = n3 + 524288, n5 = n4 + 524288;
  prep_kernel<<<(n5 + 255) / 256, 256, 0, stream>>>(
      W0, W1, W2, W3, x, b3, Wh0, Wh1, Wh2, Wh3, H, out, cnt, n0, n1, n2, n3,
      n4, n5);

  dim3 blk(256);
  gemm_bn_kernel<<<dim3(64, 8), blk, 0, stream>>>(
      H + 3072, 256, Wh0, b0, g0, be0, rm0, rv0, H, 2048);
  gemm_bn_kernel<<<dim3(64, 8), blk, 0, stream>>>(
      H + 2048, 1280, Wh1, b1, g1, be1, rm1, rv1, H, 1024);
  gemm_bn_kernel<<<dim3(64, 8), blk, 0, stream>>>(
      H + 1024, 2304, Wh2, b2, g2, be2, rm2, rv2, H, 0);
  gemm_out_kernel<<<dim3(64, 8), blk, 0, stream>>>(H, Wh3, out, seg, cnt);
}

// Round 7
// 247.173 us; speedup vs baseline: 2.5825x; 2.5350x over previous
//
#include <hip/hip_runtime.h>
#include <hip/hip_fp16.h>

// ResidualDenoiser: 4 chained GEMMs + BN/ReLU + ragged segment softmax.
// Activations live in one persistent fp16 buffer H[8192][3328] laid out
// [A3 | A2 | A1 | A0=x] so each layer's concatenated input is H + colOff.
//   layer0: in H+3072 (K= 256) -> out cols 2048:3072
//   layer1: in H+2048 (K=1280) -> out cols 1024:2048
//   layer2: in H+1024 (K=2304) -> out cols    0:1024
//   layer3: in H+0    (K=3328) -> splitK=4 atomicAdd fp32 into out (bias
//           pre-applied by prep), then separate segment-softmax dispatch.
// LESSONS (measured R4/R5/R6): in-kernel cross-block sync (grid barriers,
// last-arriver counters, agent fences) costs 300-450 us on this 8-XCD part —
// dispatch boundaries ARE the cheap sync. Keep separate dispatches.
// GEMM tile: BM=BN=128, 4 waves (2x2) each 64x64, 16x16x32 f16 MFMA.
// Layers 0-2 use BK=128 (64 KB LDS): halves barrier-drain count vs BK=64;
// zero occupancy cost because grid(512)=2 blocks/CU already caps occupancy.

#define LDH 3328
#define NROWS 8192

typedef _Float16 f16x8 __attribute__((ext_vector_type(8)));
typedef _Float16 f16x4 __attribute__((ext_vector_type(4)));
typedef float f32x4 __attribute__((ext_vector_type(4)));

__constant__ int c_bnd[11] = {0, 2, 5, 10, 18, 31, 52, 86, 141, 230, 256};

// async global->LDS, 16B per lane; LDS dest is wave-uniform base + lane*16.
__device__ __forceinline__ void async_cp16(const _Float16* g, _Float16* l) {
  __builtin_amdgcn_global_load_lds(
      (__attribute__((address_space(1))) void*)g,
      (__attribute__((address_space(3))) void*)l, 16, 0, 0);
}

__device__ __forceinline__ _Float16 f2h(float f) { return (_Float16)f; }

// ---------------------------------------------------------------------------
// prep: weights fp32->fp16 (contiguous), x staged into H, out = bias.
// One float4-group per thread.
__global__ void prep_kernel(const float* __restrict__ s0,
                            const float* __restrict__ s1,
                            const float* __restrict__ s2,
                            const float* __restrict__ s3,
                            const float* __restrict__ x,
                            const float* __restrict__ b3,
                            _Float16* __restrict__ d0,
                            _Float16* __restrict__ d1,
                            _Float16* __restrict__ d2,
                            _Float16* __restrict__ d3,
                            _Float16* __restrict__ H, float* __restrict__ out,
                            int n0, int n1, int n2, int n3, int n4, int n5) {
  int i = blockIdx.x * blockDim.x + threadIdx.x;
  if (i >= n5) return;
  if (i >= n4) {  // out[8192][256] = broadcast bias b3
    const int j = i - n4;
    const int c = (j & 63) * 4;
    *(float4*)&out[(size_t)j * 4] = *(const float4*)&b3[c];
    return;
  }
  if (i >= n3) {  // x[8192,256] -> H[:, 3072:3328]
    const int j = i - n3;
    const int row = j >> 6;
    const int c = (j & 63) * 4;
    const float4 v = *(const float4*)&x[(size_t)j * 4];
    f16x4 h = {f2h(v.x), f2h(v.y), f2h(v.z), f2h(v.w)};
    *(f16x4*)&H[(size_t)row * LDH + 3072 + c] = h;
    return;
  }
  const float* s;
  _Float16* d;
  if (i < n0) {
    s = s0; d = d0;
  } else if (i < n1) {
    s = s1 - (size_t)n0 * 4; d = d1 - (size_t)n0 * 4;
  } else if (i < n2) {
    s = s2 - (size_t)n1 * 4; d = d2 - (size_t)n1 * 4;
  } else {
    s = s3 - (size_t)n2 * 4; d = d3 - (size_t)n2 * 4;
  }
  const float4 v = *(const float4*)&s[(size_t)i * 4];
  f16x4 h = {f2h(v.x), f2h(v.y), f2h(v.z), f2h(v.w)};
  *(f16x4*)&d[(size_t)i * 4] = h;
}

// ---------------------------------------------------------------------------
// Layers 0-2: C = relu(bn(A[128,K] @ W[128,K]^T)) -> fp16 into H.
// Grid dim3(64,8). BK=128: LDS tiles are 128 rows x 128 cols fp16 (32 KB
// each). Row layout: 16 chunks of 16B, chunk c of row r stored at slot
// c ^ (r&7) (XOR swizzle -> conflict-free ds_read_b128, and staging lands
// at wave-uniform-base + lane*16 exactly).
__launch_bounds__(256, 2) __global__
void gemm_bn_kernel(const _Float16* __restrict__ A, int K,
                    const _Float16* __restrict__ W,
                    const float* __restrict__ bias,
                    const float* __restrict__ g, const float* __restrict__ be,
                    const float* __restrict__ rm,
                    const float* __restrict__ rv, _Float16* __restrict__ outH,
                    int outOff) {
  __shared__ _Float16 Alds[128 * 128];  // 32 KB
  __shared__ _Float16 Blds[128 * 128];  // 32 KB

  const int tid = threadIdx.x;
  const int lane = tid & 63;
  const int wave = tid >> 6;          // 0..3
  const int wr = wave >> 1;           // 64-row half
  const int wc = wave & 1;            // 64-col half
  const int row0 = blockIdx.x * 128;  // M block
  const int col0 = blockIdx.y * 128;  // N block
  // staging lane decomposition: each cp16 instr covers 4 rows x 16 chunks
  const int lr4 = lane >> 4;  // row within 4-row group
  const int sl = lane & 15;   // lds slot within row
  // fragment lane decomposition (16x16x32 MFMA)
  const int fr = lane & 15;  // m (A) / n (B) index
  const int q = lane >> 4;   // quad: k = q*8 + j

  f32x4 acc[4][4] = {};

  for (int k0 = 0; k0 < K; k0 += 128) {
    __syncthreads();  // previous-iter consumers done before overwrite
#pragma unroll
    for (int it = 0; it < 8; ++it) {
      const int j = it * 4 + wave;     // instr id 0..31
      const int r = j * 4 + lr4;       // tile row 0..127
      const int gc = sl ^ (r & 7);     // global chunk fetched into slot sl
      async_cp16(A + (size_t)(row0 + r) * LDH + k0 + gc * 8, &Alds[j * 512]);
      async_cp16(W + (size_t)(col0 + r) * K + k0 + gc * 8, &Blds[j * 512]);
    }
    __syncthreads();  // drains vmcnt: staging complete

#pragma unroll
    for (int kq = 0; kq < 4; ++kq) {
      f16x8 av[4], bv[4];
#pragma unroll
      for (int t = 0; t < 4; ++t) {
        const int ra = wr * 64 + t * 16 + fr;
        av[t] =
            *(const f16x8*)&Alds[ra * 128 + (((kq * 4 + q) ^ (ra & 7)) * 8)];
        const int rb = wc * 64 + t * 16 + fr;
        bv[t] =
            *(const f16x8*)&Blds[rb * 128 + (((kq * 4 + q) ^ (rb & 7)) * 8)];
      }
#pragma unroll
      for (int tm = 0; tm < 4; ++tm)
#pragma unroll
        for (int tn = 0; tn < 4; ++tn)
          acc[tm][tn] = __builtin_amdgcn_mfma_f32_16x16x32_f16(
              av[tm], bv[tn], acc[tm][tn], 0, 0, 0);
    }
  }

  // Epilogue. C/D layout: col = lane&15, row = (lane>>4)*4 + reg.
#pragma unroll
  for (int tn = 0; tn < 4; ++tn) {
    const int n = col0 + wc * 64 + tn * 16 + fr;
    const float alpha = g[n] * rsqrtf(rv[n] + 1e-5f);
    const float beta = (bias[n] - rm[n]) * alpha + be[n];
#pragma unroll
    for (int tm = 0; tm < 4; ++tm) {
      const int rbase = row0 + wr * 64 + tm * 16 + q * 4;
#pragma unroll
      for (int r = 0; r < 4; ++r) {
        float v = acc[tm][tn][r] * alpha + beta;
        v = fmaxf(v, 0.0f);
        outH[(size_t)(rbase + r) * LDH + outOff + n] = f2h(v);
      }
    }
  }
}

// ---------------------------------------------------------------------------
// Layer 3: splitK=4, BK=64 (832 = 13*64 per slice). Grid dim3(64,8):
// cb=by&1 (col tile), ks=by>>1. Partials atomicAdd into out (bias
// pre-applied by prep). R2's exact proven body.
__launch_bounds__(256, 4) __global__
void gemm_out_kernel(const _Float16* __restrict__ A,
                     const _Float16* __restrict__ W,
                     float* __restrict__ out) {
  __shared__ _Float16 Alds[128 * 64];
  __shared__ _Float16 Blds[128 * 64];

  const int tid = threadIdx.x;
  const int lane = tid & 63;
  const int wave = tid >> 6;
  const int wr = wave >> 1;
  const int wc = wave & 1;
  const int row0 = blockIdx.x * 128;
  const int cb = blockIdx.y & 1;
  const int ks = blockIdx.y >> 1;
  const int col0 = cb * 128;
  const int k0b = ks * 832;
  const int k0e = k0b + 832;
  const int lr = lane >> 3;  // staging: 8 rows x 8 16B-chunks
  const int ls = lane & 7;
  const int lc = ls ^ lr;
  const int fr = lane & 15;
  const int q = lane >> 4;
  const int K = 3328;

  f32x4 acc[4][4] = {};

  for (int k0 = k0b; k0 < k0e; k0 += 64) {
    __syncthreads();
#pragma unroll
    for (int it = 0; it < 4; ++it) {
      const int rl = it * 32 + wave * 8;
      async_cp16(A + (size_t)(row0 + rl + lr) * LDH + k0 + lc * 8,
                 &Alds[rl * 64]);
      async_cp16(W + (size_t)(col0 + rl + lr) * K + k0 + lc * 8,
                 &Blds[rl * 64]);
    }
    __syncthreads();

#pragma unroll
    for (int kq = 0; kq < 2; ++kq) {
      f16x8 av[4], bv[4];
#pragma unroll
      for (int t = 0; t < 4; ++t) {
        const int ra = wr * 64 + t * 16 + fr;
        av[t] = *(const f16x8*)&Alds[ra * 64 + (((q + 4 * kq) ^ (ra & 7)) * 8)];
        const int rb = wc * 64 + t * 16 + fr;
        bv[t] = *(const f16x8*)&Blds[rb * 64 + (((q + 4 * kq) ^ (rb & 7)) * 8)];
      }
#pragma unroll
      for (int tm = 0; tm < 4; ++tm)
#pragma unroll
        for (int tn = 0; tn < 4; ++tn)
          acc[tm][tn] = __builtin_amdgcn_mfma_f32_16x16x32_f16(
              av[tm], bv[tn], acc[tm][tn], 0, 0, 0);
    }
  }

#pragma unroll
  for (int tn = 0; tn < 4; ++tn) {
    const int n = col0 + wc * 64 + tn * 16 + fr;
#pragma unroll
    for (int tm = 0; tm < 4; ++tm) {
      const int rbase = row0 + wr * 64 + tm * 16 + q * 4;
#pragma unroll
      for (int r = 0; r < 4; ++r)
        atomicAdd(&out[(size_t)(rbase + r) * 256 + n], acc[tm][tn][r]);
    }
  }
}

// ---------------------------------------------------------------------------
// ragged segment softmax, in place on out[8192][256]; 4 rows/block (1/wave).
__global__ void segsoftmax_kernel(float* __restrict__ out,
                                  const int* __restrict__ segids) {
  __shared__ float vals[4][256];
  __shared__ float red[4][10];
  const int w = threadIdx.x >> 6;
  const int l = threadIdx.x & 63;
  const int row = blockIdx.x * 4 + w;
  float4 v = *(float4*)&out[(size_t)row * 256 + l * 4];
  *(float4*)&vals[w][l * 4] = v;
  __syncthreads();
  if (l < 10) {
    float m = -1e30f;
    for (int j = c_bnd[l]; j < c_bnd[l + 1]; ++j) m = fmaxf(m, vals[w][j]);
    red[w][l] = m;
  }
  __syncthreads();
  const int4 s4 = *(const int4*)&segids[l * 4];
  float4 e;
  e.x = expf(v.x - red[w][s4.x]);
  e.y = expf(v.y - red[w][s4.y]);
  e.z = expf(v.z - red[w][s4.z]);
  e.w = expf(v.w - red[w][s4.w]);
  *(float4*)&vals[w][l * 4] = e;
  __syncthreads();
  if (l < 10) {
    float s = 0.0f;
    for (int j = c_bnd[l]; j < c_bnd[l + 1]; ++j) s += vals[w][j];
    red[w][l] = s;
  }
  __syncthreads();
  float4 o;
  o.x = e.x / red[w][s4.x];
  o.y = e.y / red[w][s4.y];
  o.z = e.z / red[w][s4.z];
  o.w = e.w / red[w][s4.w];
  *(float4*)&out[(size_t)row * 256 + l * 4] = o;
}

// ---------------------------------------------------------------------------
extern "C" void kernel_launch(void* const* d_in, const int* in_sizes, int n_in,
                              void* d_out, int out_size, void* d_ws,
                              size_t ws_size, hipStream_t stream) {
  const float* x = (const float*)d_in[0];
  const float* W0 = (const float*)d_in[1];
  const float* b0 = (const float*)d_in[2];
  const float* g0 = (const float*)d_in[3];
  const float* be0 = (const float*)d_in[4];
  const float* rm0 = (const float*)d_in[5];
  const float* rv0 = (const float*)d_in[6];
  const float* W1 = (const float*)d_in[7];
  const float* b1 = (const float*)d_in[8];
  const float* g1 = (const float*)d_in[9];
  const float* be1 = (const float*)d_in[10];
  const float* rm1 = (const float*)d_in[11];
  const float* rv1 = (const float*)d_in[12];
  const float* W2 = (const float*)d_in[13];
  const float* b2 = (const float*)d_in[14];
  const float* g2 = (const float*)d_in[15];
  const float* be2 = (const float*)d_in[16];
  const float* rm2 = (const float*)d_in[17];
  const float* rv2 = (const float*)d_in[18];
  const float* W3 = (const float*)d_in[19];
  const float* b3 = (const float*)d_in[20];
  const int* seg = (const int*)d_in[21];
  float* out = (float*)d_out;

  // ws (fp16): H[8192*3328] | Wh0 | Wh1 | Wh2 | Wh3  (~64.1 MB)
  _Float16* H = (_Float16*)d_ws;
  size_t off = (size_t)NROWS * LDH;
  _Float16* Wh0 = H + off; off += 1024 * 256;
  _Float16* Wh1 = H + off; off += 1024 * 1280;
  _Float16* Wh2 = H + off; off += 1024 * 2304;
  _Float16* Wh3 = H + off;

  // cumulative float4 counts: W0, W1, W2, W3, x, out-init
  const int n0 = 65536, n1 = n0 + 327680, n2 = n1 + 589824, n3 = n2 + 212992;
  const int n4 = n3 + 524288, n5 = n4 + 524288;
  prep_kernel<<<(n5 + 255) / 256, 256, 0, stream>>>(
      W0, W1, W2, W3, x, b3, Wh0, Wh1, Wh2, Wh3, H, out, n0, n1, n2, n3, n4,
      n5);

  dim3 blk(256);
  gemm_bn_kernel<<<dim3(64, 8), blk, 0, stream>>>(
      H + 3072, 256, Wh0, b0, g0, be0, rm0, rv0, H, 2048);
  gemm_bn_kernel<<<dim3(64, 8), blk, 0, stream>>>(
      H + 2048, 1280, Wh1, b1, g1, be1, rm1, rv1, H, 1024);
  gemm_bn_kernel<<<dim3(64, 8), blk, 0, stream>>>(
      H + 1024, 2304, Wh2, b2, g2, be2, rm2, rv2, H, 0);
  gemm_out_kernel<<<dim3(64, 8), blk, 0, stream>>>(H, Wh3, out);
  segsoftmax_kernel<<<2048, 256, 0, stream>>>(out, seg);
}